// Round 1
// baseline (2445.226 us; speedup 1.0000x reference)
//
#include <hip/hip_runtime.h>

// Problem constants (from reference): N=2048, D=512, A=64, NQ=8, G1=G2=8, A1=128.
//
// KEY ALGEBRA: no softmax => ctx = q @ (K^T V)/sqrt(a). Everything folds into
// per-group 512x512 matrices:
//   S[g]  = (x Wk + bk)^T (x Wv + bv) / sqrt(a)          [a,a]
//   M[g]  = sum_q Wq[g,q] @ S[g] @ Wo_q[g,q]             [D,D]
//   c[g]  = sum_q (bq[g,q] @ S[g]) @ Wo_q[g,q] + bo[g]   [D]
//   o[g]  = x @ M[g] + c[g]
// Tier2 same on o1; final @Wo folds into M2' = M2 @ Wo, c2' = c2 @ Wo + bo.
// Total ~34 GFLOP of GEMMs (vs ~272 GFLOP naive).

// ---------------- Generic tiled fp32 GEMM ----------------
// C = alpha * op(A) @ B (+ bias row per batch).  TA: A indexed as A[k,m].
// Batch b decomposes as (go = b/divq, gi = b%divq); per-matrix offsets
// off = go*Out + gi*In lets one kernel express "Wq1[g,q] @ S1[g] -> T[g][:,q*A1:]".
template<bool TA>
__global__ __launch_bounds__(256) void gemm_f32(
    const float* __restrict__ A, const float* __restrict__ B,
    const float* __restrict__ bias, float* __restrict__ C,
    int M, int N, int K, int lda, int ldb, int ldc,
    int divq, long aOut, long aIn, long bOut, long bIn,
    long cOut, long cIn, long biasOut, int hasBias, float alpha)
{
    constexpr int BM = 64, BN = 64, BK = 16;
    __shared__ float As[BK][BM];
    __shared__ float Bs[BK][BN];

    int b  = blockIdx.z;
    int go = b / divq, gi = b - go * divq;
    A += (long)go * aOut + (long)gi * aIn;
    B += (long)go * bOut + (long)gi * bIn;
    C += (long)go * cOut + (long)gi * cIn;
    if (hasBias) bias += (long)go * biasOut;

    int bm = blockIdx.y * BM, bn = blockIdx.x * BN;
    int tid = threadIdx.x;
    int tx = tid & 15, ty = tid >> 4;   // 16x16 threads, 4x4 micro-tile each

    float acc[4][4] = {};

    for (int k0 = 0; k0 < K; k0 += BK) {
        if (!TA) {
            #pragma unroll
            for (int t = 0; t < 4; ++t) {
                int idx = tid + t * 256;
                int i = idx >> 4, kk = idx & 15;
                int gr = bm + i, gc = k0 + kk;
                As[kk][i] = (gr < M && gc < K) ? A[(long)gr * lda + gc] : 0.0f;
            }
        } else {
            #pragma unroll
            for (int t = 0; t < 4; ++t) {
                int idx = tid + t * 256;
                int i = idx & 63, kk = idx >> 6;
                int gr = k0 + kk, gc = bm + i;
                As[kk][i] = (gr < K && gc < M) ? A[(long)gr * lda + gc] : 0.0f;
            }
        }
        #pragma unroll
        for (int t = 0; t < 4; ++t) {
            int idx = tid + t * 256;
            int j = idx & 63, kk = idx >> 6;
            int gr = k0 + kk, gc = bn + j;
            Bs[kk][j] = (gr < K && gc < N) ? B[(long)gr * ldb + gc] : 0.0f;
        }
        __syncthreads();

        #pragma unroll
        for (int kk = 0; kk < BK; ++kk) {
            float4 a4 = *(const float4*)(&As[kk][ty * 4]);
            float4 b4 = *(const float4*)(&Bs[kk][tx * 4]);
            float av[4] = {a4.x, a4.y, a4.z, a4.w};
            float bv[4] = {b4.x, b4.y, b4.z, b4.w};
            #pragma unroll
            for (int i = 0; i < 4; ++i)
                #pragma unroll
                for (int j = 0; j < 4; ++j)
                    acc[i][j] += av[i] * bv[j];
        }
        __syncthreads();
    }

    #pragma unroll
    for (int i = 0; i < 4; ++i) {
        int r = bm + ty * 4 + i;
        if (r >= M) continue;
        #pragma unroll
        for (int j = 0; j < 4; ++j) {
            int c = bn + tx * 4 + j;
            if (c >= N) continue;
            float v = acc[i][j] * alpha;
            if (hasBias) v += bias[c];
            C[(long)r * ldc + c] = v;
        }
    }
}

// r[g, q*ad + a] = sum_c bq[g,q,c] * S[g,c,a]   (S already includes 1/sqrt(a))
__global__ void bqS_kernel(const float* __restrict__ bq, const float* __restrict__ S,
                           float* __restrict__ r, int nq, int ad)
{
    int g = blockIdx.x / nq, q = blockIdx.x - g * nq;
    int a = threadIdx.x;
    const float* bqv = bq + (long)(g * nq + q) * ad;
    const float* Sg  = S + (long)g * ad * ad;
    float s = 0.0f;
    for (int c = 0; c < ad; ++c) s += bqv[c] * Sg[(long)c * ad + a];
    r[(long)(g * nq + q) * ad + a] = s;
}

// out[g,d] = sum_f r[g,f] * W[g? f,d] + bvec[g? d]   (wStride/bStride==0 => shared)
__global__ void rowmat_kernel(const float* __restrict__ r, const float* __restrict__ W,
                              const float* __restrict__ bvec, float* __restrict__ out,
                              int F, int Dd, long rStride, long wStride, long bStride)
{
    int g = blockIdx.x;
    int d = threadIdx.x + blockIdx.y * blockDim.x;
    if (d >= Dd) return;
    const float* rg = r + (long)g * rStride;
    const float* Wg = W + (long)g * wStride;
    float s = bvec[(long)g * bStride + d];
    for (int f = 0; f < F; ++f) s += rg[f] * Wg[(long)f * Dd + d];
    out[(long)g * Dd + d] = s;
}

extern "C" void kernel_launch(void* const* d_in, const int* in_sizes, int n_in,
                              void* d_out, int out_size, void* d_ws, size_t ws_size,
                              hipStream_t stream)
{
    const float* x   = (const float*)d_in[0];
    const float* Wq1 = (const float*)d_in[1];
    const float* bq1 = (const float*)d_in[2];
    const float* Wk1 = (const float*)d_in[3];
    const float* bk1 = (const float*)d_in[4];
    const float* Wv1 = (const float*)d_in[5];
    const float* bv1 = (const float*)d_in[6];
    const float* Wo1 = (const float*)d_in[7];
    const float* bo1 = (const float*)d_in[8];
    const float* Wq2 = (const float*)d_in[9];
    const float* bq2 = (const float*)d_in[10];
    const float* Wk2 = (const float*)d_in[11];
    const float* bk2 = (const float*)d_in[12];
    const float* Wv2 = (const float*)d_in[13];
    const float* bv2 = (const float*)d_in[14];
    const float* Wo2 = (const float*)d_in[15];
    const float* bo2 = (const float*)d_in[16];
    const float* Wo  = (const float*)d_in[17];
    const float* bo  = (const float*)d_in[18];
    float* out = (float*)d_out;
    float* ws  = (float*)d_ws;

    // Workspace layout (floats). Tier2 reuses tier1 buffers. Total ~21.2M floats (~84.5 MB).
    size_t off = 0;
    float* Kbuf = ws + off; off += 8L * 2048 * 128;   // K1 (tier2 K2 reuses)
    float* Vbuf = ws + off; off += 8L * 2048 * 128;   // V1 / V2
    float* Sbuf = ws + off; off += 8L * 128 * 128;    // S1 / S2
    float* Tbuf = ws + off; off += 8L * 512 * 1024;   // T1 / T2
    float* Mbuf = ws + off; off += 8L * 512 * 512;    // M1 / M2
    float* o1b  = ws + off; off += 8L * 2048 * 512;   // o1 (live till the end)
    float* M2p  = ws + off; off += 8L * 512 * 512;    // M2 @ Wo
    float* r1   = ws + off; off += 8L * 1024;
    float* c1   = ws + off; off += 8L * 512;
    float* r2   = ws + off; off += 8L * 512;
    float* c2   = ws + off; off += 8L * 512;
    float* c2p  = ws + off; off += 8L * 512;
    (void)ws_size; (void)n_in; (void)in_sizes; (void)out_size;

    dim3 blk(256);
    const float inv_sqrt_a1 = 0.08838834764831845f;  // 1/sqrt(128)
    const float inv_sqrt_a2 = 0.125f;                // 1/sqrt(64)

    // ---- Tier 1 ----
    // K1[g] = x @ Wk1[g] + bk1[g]    [2048,128]
    gemm_f32<false><<<dim3(2, 32, 8), blk, 0, stream>>>(x, Wk1, bk1, Kbuf,
        2048, 128, 512, 512, 128, 128,
        1, 0L, 0L, 65536L, 0L, 262144L, 0L, 128L, 1, 1.0f);
    // V1[g] = x @ Wv1[g] + bv1[g]
    gemm_f32<false><<<dim3(2, 32, 8), blk, 0, stream>>>(x, Wv1, bv1, Vbuf,
        2048, 128, 512, 512, 128, 128,
        1, 0L, 0L, 65536L, 0L, 262144L, 0L, 128L, 1, 1.0f);
    // S1[g] = K1^T V1 / sqrt(128)    [128,128]
    gemm_f32<true><<<dim3(2, 2, 8), blk, 0, stream>>>(Kbuf, Vbuf, nullptr, Sbuf,
        128, 128, 2048, 128, 128, 128,
        1, 262144L, 0L, 262144L, 0L, 16384L, 0L, 0L, 0, inv_sqrt_a1);
    // T1[g][:, q*128: ] = Wq1[g,q] @ S1[g]   [512,128] per (g,q), ldc=1024
    gemm_f32<false><<<dim3(2, 8, 64), blk, 0, stream>>>(Wq1, Sbuf, nullptr, Tbuf,
        512, 128, 128, 128, 128, 1024,
        8, 524288L, 65536L, 16384L, 0L, 524288L, 128L, 0L, 0, 1.0f);
    // M1[g] = T1[g] @ Wo1[g]    [512,1024]@[1024,512]
    gemm_f32<false><<<dim3(8, 8, 8), blk, 0, stream>>>(Tbuf, Wo1, nullptr, Mbuf,
        512, 512, 1024, 1024, 512, 512,
        1, 524288L, 0L, 524288L, 0L, 262144L, 0L, 0L, 0, 1.0f);
    // r1[g] = bq1[g,:] @ S1[g] (per q);  c1[g] = r1[g] @ Wo1[g] + bo1[g]
    bqS_kernel<<<dim3(64), dim3(128), 0, stream>>>(bq1, Sbuf, r1, 8, 128);
    rowmat_kernel<<<dim3(8, 2), blk, 0, stream>>>(r1, Wo1, bo1, c1,
        1024, 512, 1024L, 524288L, 512L);
    // o1[g] = x @ M1[g] + c1[g]    [2048,512]
    gemm_f32<false><<<dim3(8, 32, 8), blk, 0, stream>>>(x, Mbuf, c1, o1b,
        2048, 512, 512, 512, 512, 512,
        1, 0L, 0L, 262144L, 0L, 1048576L, 0L, 512L, 1, 1.0f);

    // ---- Tier 2 (input o1) ----
    gemm_f32<false><<<dim3(1, 32, 8), blk, 0, stream>>>(o1b, Wk2, bk2, Kbuf,
        2048, 64, 512, 512, 64, 64,
        1, 1048576L, 0L, 32768L, 0L, 131072L, 0L, 64L, 1, 1.0f);
    gemm_f32<false><<<dim3(1, 32, 8), blk, 0, stream>>>(o1b, Wv2, bv2, Vbuf,
        2048, 64, 512, 512, 64, 64,
        1, 1048576L, 0L, 32768L, 0L, 131072L, 0L, 64L, 1, 1.0f);
    gemm_f32<true><<<dim3(1, 1, 8), blk, 0, stream>>>(Kbuf, Vbuf, nullptr, Sbuf,
        64, 64, 2048, 64, 64, 64,
        1, 131072L, 0L, 131072L, 0L, 4096L, 0L, 0L, 0, inv_sqrt_a2);
    gemm_f32<false><<<dim3(1, 8, 64), blk, 0, stream>>>(Wq2, Sbuf, nullptr, Tbuf,
        512, 64, 64, 64, 64, 512,
        8, 262144L, 32768L, 4096L, 0L, 262144L, 64L, 0L, 0, 1.0f);
    gemm_f32<false><<<dim3(8, 8, 8), blk, 0, stream>>>(Tbuf, Wo2, nullptr, Mbuf,
        512, 512, 512, 512, 512, 512,
        1, 262144L, 0L, 262144L, 0L, 262144L, 0L, 0L, 0, 1.0f);
    bqS_kernel<<<dim3(64), dim3(64), 0, stream>>>(bq2, Sbuf, r2, 8, 64);
    rowmat_kernel<<<dim3(8, 2), blk, 0, stream>>>(r2, Wo2, bo2, c2,
        512, 512, 512L, 262144L, 512L);

    // ---- Fold final projection ----
    // M2p[g] = M2[g] @ Wo ; c2p[g] = c2[g] @ Wo + bo
    gemm_f32<false><<<dim3(8, 8, 8), blk, 0, stream>>>(Mbuf, Wo, nullptr, M2p,
        512, 512, 512, 512, 512, 512,
        1, 262144L, 0L, 0L, 0L, 262144L, 0L, 0L, 0, 1.0f);
    rowmat_kernel<<<dim3(8, 2), blk, 0, stream>>>(c2, Wo, bo, c2p,
        512, 512, 512L, 0L, 0L);

    // out[g] = o1[g] @ M2p[g] + c2p[g]   -> d_out [G2*N, D]
    gemm_f32<false><<<dim3(8, 32, 8), blk, 0, stream>>>(o1b, M2p, c2p, out,
        2048, 512, 512, 512, 512, 512,
        1, 1048576L, 0L, 262144L, 0L, 1048576L, 0L, 512L, 1, 1.0f);
}

// Round 2
// 1549.329 us; speedup vs baseline: 1.5782x; 1.5782x over previous
//
#include <hip/hip_runtime.h>

// N=2048, D=512, A=64, NQ=8, G1=G2=8, A1=128.
// Algebra (no softmax): ctx = q @ (K^T V)/sqrt(a) => per-group fold:
//   S[g] = (xWk+bk)^T (xWv+bv)/sqrt(a);  M[g] = sum_q Wq[g,q] S[g] Wo_q[g,q]
//   o[g] = x M[g] + c[g];  tier2 same;  final @Wo folds into M2' = M2 Wo.
// ~34 GFLOP of GEMMs. This round: bf16 MFMA GEMM (fp32 accum), conversion
// fused into LDS staging.

typedef __bf16 bf16x8 __attribute__((ext_vector_type(8)));
typedef __bf16 bf16x4 __attribute__((ext_vector_type(4)));
typedef float  f32x4  __attribute__((ext_vector_type(4)));

// ---------------- bf16 MFMA GEMM ----------------
// C = alpha * op(A) @ B (+ bias row). TA: A indexed as A[k,m] (lda = m-stride).
// Batch b: (go = b/divq, gi = b%divq); ptr += go*Out + gi*In.
// Requires: K % 32 == 0, all dims % 4 == 0 (true for this problem).
template<bool TA>
__global__ __launch_bounds__(256) void gemm_bf16(
    const float* __restrict__ A, const float* __restrict__ B,
    const float* __restrict__ bias, float* __restrict__ C,
    int M, int N, int K, int lda, int ldb, int ldc,
    int divq, long aOut, long aIn, long bOut, long bIn,
    long cOut, long cIn, long biasOut, int hasBias, float alpha)
{
    constexpr int BM = 128, BN = 128, BK = 32, LDP = BK + 8; // pad to 40
    __shared__ __bf16 As[BM][LDP];   // As[m][k]
    __shared__ __bf16 Bs[BN][LDP];   // Bs[n][k]

    int b  = blockIdx.z;
    int go = b / divq, gi = b - go * divq;
    A += (long)go * aOut + (long)gi * aIn;
    B += (long)go * bOut + (long)gi * bIn;
    C += (long)go * cOut + (long)gi * cIn;
    if (hasBias) bias += (long)go * biasOut;

    int bm = blockIdx.y * BM, bn = blockIdx.x * BN;
    int tid  = threadIdx.x;
    int wave = tid >> 6, lane = tid & 63;
    int wm = (wave >> 1) * 64, wn = (wave & 1) * 64;
    int mrow = lane & 15, quad = lane >> 4;

    f32x4 acc[4][4];
    #pragma unroll
    for (int i = 0; i < 4; ++i)
        #pragma unroll
        for (int j = 0; j < 4; ++j)
            acc[i][j] = f32x4{0.f, 0.f, 0.f, 0.f};

    for (int k0 = 0; k0 < K; k0 += BK) {
        // ---- stage A ----
        if (!TA) {
            // A[M][K] row-major: thread loads float4 along k, writes 4 bf16 (8B).
            #pragma unroll
            for (int t = 0; t < 4; ++t) {
                int idx = tid + t * 256;          // [0,1024)
                int row = idx >> 3, kq = idx & 7; // kq*4 in [0,32)
                bf16x4 v;
                if (bm + row < M) {
                    float4 f = *(const float4*)(A + (long)(bm + row) * lda + k0 + kq * 4);
                    v = bf16x4{(__bf16)f.x, (__bf16)f.y, (__bf16)f.z, (__bf16)f.w};
                } else {
                    v = bf16x4{(__bf16)0.f, (__bf16)0.f, (__bf16)0.f, (__bf16)0.f};
                }
                *(bf16x4*)&As[row][kq * 4] = v;
            }
        } else {
            // A indexed [K][M] (lda = m-stride): load float4 along m, scatter-transpose.
            #pragma unroll
            for (int t = 0; t < 4; ++t) {
                int idx = tid + t * 256;
                int kk = idx >> 5, mq = idx & 31;   // kk in [0,32), mq*4 in [0,128)
                float4 f = {0.f, 0.f, 0.f, 0.f};
                if (bm + mq * 4 < M)
                    f = *(const float4*)(A + (long)(k0 + kk) * lda + bm + mq * 4);
                As[mq * 4 + 0][kk] = (__bf16)f.x;
                As[mq * 4 + 1][kk] = (__bf16)f.y;
                As[mq * 4 + 2][kk] = (__bf16)f.z;
                As[mq * 4 + 3][kk] = (__bf16)f.w;
            }
        }
        // ---- stage B ([K][N] row-major -> Bs[n][k]) ----
        #pragma unroll
        for (int t = 0; t < 4; ++t) {
            int idx = tid + t * 256;
            int kk = idx >> 5, nq = idx & 31;
            float4 f = {0.f, 0.f, 0.f, 0.f};
            if (bn + nq * 4 < N)
                f = *(const float4*)(B + (long)(k0 + kk) * ldb + bn + nq * 4);
            Bs[nq * 4 + 0][kk] = (__bf16)f.x;
            Bs[nq * 4 + 1][kk] = (__bf16)f.y;
            Bs[nq * 4 + 2][kk] = (__bf16)f.z;
            Bs[nq * 4 + 3][kk] = (__bf16)f.w;
        }
        __syncthreads();

        // ---- MFMA: one 16x16x32 covers the whole BK per (mt,nt) ----
        bf16x8 af[4], bfv[4];
        #pragma unroll
        for (int mt = 0; mt < 4; ++mt)
            af[mt] = *(const bf16x8*)&As[wm + mt * 16 + mrow][quad * 8];
        #pragma unroll
        for (int nt = 0; nt < 4; ++nt)
            bfv[nt] = *(const bf16x8*)&Bs[wn + nt * 16 + mrow][quad * 8];
        #pragma unroll
        for (int mt = 0; mt < 4; ++mt)
            #pragma unroll
            for (int nt = 0; nt < 4; ++nt)
                acc[mt][nt] = __builtin_amdgcn_mfma_f32_16x16x32_bf16(
                    af[mt], bfv[nt], acc[mt][nt], 0, 0, 0);
        __syncthreads();
    }

    // ---- epilogue: reg r of lane -> C[row = quad*4 + r][col = lane&15] ----
    #pragma unroll
    for (int mt = 0; mt < 4; ++mt) {
        #pragma unroll
        for (int r = 0; r < 4; ++r) {
            int row = bm + wm + mt * 16 + quad * 4 + r;
            if (row >= M) continue;
            #pragma unroll
            for (int nt = 0; nt < 4; ++nt) {
                int col = bn + wn + nt * 16 + mrow;
                if (col >= N) continue;
                float v = acc[mt][nt][r] * alpha;
                if (hasBias) v += bias[col];
                C[(long)row * ldc + col] = v;
            }
        }
    }
}

// r[g, q*ad + a] = sum_c bq[g,q,c] * S[g,c,a]
__global__ void bqS_kernel(const float* __restrict__ bq, const float* __restrict__ S,
                           float* __restrict__ r, int nq, int ad)
{
    int g = blockIdx.x / nq, q = blockIdx.x - g * nq;
    int a = threadIdx.x;
    const float* bqv = bq + (long)(g * nq + q) * ad;
    const float* Sg  = S + (long)g * ad * ad;
    float s = 0.0f;
    for (int c = 0; c < ad; ++c) s += bqv[c] * Sg[(long)c * ad + a];
    r[(long)(g * nq + q) * ad + a] = s;
}

// out[g,d] = sum_f r[g,f] * W[g? f,d] + bvec[g? d]
__global__ void rowmat_kernel(const float* __restrict__ r, const float* __restrict__ W,
                              const float* __restrict__ bvec, float* __restrict__ out,
                              int F, int Dd, long rStride, long wStride, long bStride)
{
    int g = blockIdx.x;
    int d = threadIdx.x + blockIdx.y * blockDim.x;
    if (d >= Dd) return;
    const float* rg = r + (long)g * rStride;
    const float* Wg = W + (long)g * wStride;
    float s = bvec[(long)g * bStride + d];
    for (int f = 0; f < F; ++f) s += rg[f] * Wg[(long)f * Dd + d];
    out[(long)g * Dd + d] = s;
}

extern "C" void kernel_launch(void* const* d_in, const int* in_sizes, int n_in,
                              void* d_out, int out_size, void* d_ws, size_t ws_size,
                              hipStream_t stream)
{
    const float* x   = (const float*)d_in[0];
    const float* Wq1 = (const float*)d_in[1];
    const float* bq1 = (const float*)d_in[2];
    const float* Wk1 = (const float*)d_in[3];
    const float* bk1 = (const float*)d_in[4];
    const float* Wv1 = (const float*)d_in[5];
    const float* bv1 = (const float*)d_in[6];
    const float* Wo1 = (const float*)d_in[7];
    const float* bo1 = (const float*)d_in[8];
    const float* Wq2 = (const float*)d_in[9];
    const float* bq2 = (const float*)d_in[10];
    const float* Wk2 = (const float*)d_in[11];
    const float* bk2 = (const float*)d_in[12];
    const float* Wv2 = (const float*)d_in[13];
    const float* bv2 = (const float*)d_in[14];
    const float* Wo2 = (const float*)d_in[15];
    const float* bo2 = (const float*)d_in[16];
    const float* Wo  = (const float*)d_in[17];
    const float* bo  = (const float*)d_in[18];
    float* out = (float*)d_out;
    float* ws  = (float*)d_ws;

    size_t off = 0;
    float* Kbuf = ws + off; off += 8L * 2048 * 128;
    float* Vbuf = ws + off; off += 8L * 2048 * 128;
    float* Sbuf = ws + off; off += 8L * 128 * 128;
    float* Tbuf = ws + off; off += 8L * 512 * 1024;
    float* Mbuf = ws + off; off += 8L * 512 * 512;
    float* o1b  = ws + off; off += 8L * 2048 * 512;
    float* M2p  = ws + off; off += 8L * 512 * 512;
    float* r1   = ws + off; off += 8L * 1024;
    float* c1   = ws + off; off += 8L * 512;
    float* r2   = ws + off; off += 8L * 512;
    float* c2   = ws + off; off += 8L * 512;
    float* c2p  = ws + off; off += 8L * 512;
    (void)ws_size; (void)n_in; (void)in_sizes; (void)out_size;

    dim3 blk(256);
    const float inv_sqrt_a1 = 0.08838834764831845f;  // 1/sqrt(128)
    const float inv_sqrt_a2 = 0.125f;                // 1/sqrt(64)

    // ---- Tier 1 ----
    gemm_bf16<false><<<dim3(1, 16, 8), blk, 0, stream>>>(x, Wk1, bk1, Kbuf,
        2048, 128, 512, 512, 128, 128,
        1, 0L, 0L, 65536L, 0L, 262144L, 0L, 128L, 1, 1.0f);
    gemm_bf16<false><<<dim3(1, 16, 8), blk, 0, stream>>>(x, Wv1, bv1, Vbuf,
        2048, 128, 512, 512, 128, 128,
        1, 0L, 0L, 65536L, 0L, 262144L, 0L, 128L, 1, 1.0f);
    gemm_bf16<true><<<dim3(1, 1, 8), blk, 0, stream>>>(Kbuf, Vbuf, nullptr, Sbuf,
        128, 128, 2048, 128, 128, 128,
        1, 262144L, 0L, 262144L, 0L, 16384L, 0L, 0L, 0, inv_sqrt_a1);
    gemm_bf16<false><<<dim3(1, 4, 64), blk, 0, stream>>>(Wq1, Sbuf, nullptr, Tbuf,
        512, 128, 128, 128, 128, 1024,
        8, 524288L, 65536L, 16384L, 0L, 524288L, 128L, 0L, 0, 1.0f);
    gemm_bf16<false><<<dim3(4, 4, 8), blk, 0, stream>>>(Tbuf, Wo1, nullptr, Mbuf,
        512, 512, 1024, 1024, 512, 512,
        1, 524288L, 0L, 524288L, 0L, 262144L, 0L, 0L, 0, 1.0f);
    bqS_kernel<<<dim3(64), dim3(128), 0, stream>>>(bq1, Sbuf, r1, 8, 128);
    rowmat_kernel<<<dim3(8, 2), blk, 0, stream>>>(r1, Wo1, bo1, c1,
        1024, 512, 1024L, 524288L, 512L);
    gemm_bf16<false><<<dim3(4, 16, 8), blk, 0, stream>>>(x, Mbuf, c1, o1b,
        2048, 512, 512, 512, 512, 512,
        1, 0L, 0L, 262144L, 0L, 1048576L, 0L, 512L, 1, 1.0f);

    // ---- Tier 2 ----
    gemm_bf16<false><<<dim3(1, 16, 8), blk, 0, stream>>>(o1b, Wk2, bk2, Kbuf,
        2048, 64, 512, 512, 64, 64,
        1, 1048576L, 0L, 32768L, 0L, 131072L, 0L, 64L, 1, 1.0f);
    gemm_bf16<false><<<dim3(1, 16, 8), blk, 0, stream>>>(o1b, Wv2, bv2, Vbuf,
        2048, 64, 512, 512, 64, 64,
        1, 1048576L, 0L, 32768L, 0L, 131072L, 0L, 64L, 1, 1.0f);
    gemm_bf16<true><<<dim3(1, 1, 8), blk, 0, stream>>>(Kbuf, Vbuf, nullptr, Sbuf,
        64, 64, 2048, 64, 64, 64,
        1, 131072L, 0L, 131072L, 0L, 4096L, 0L, 0L, 0, inv_sqrt_a2);
    gemm_bf16<false><<<dim3(1, 4, 64), blk, 0, stream>>>(Wq2, Sbuf, nullptr, Tbuf,
        512, 64, 64, 64, 64, 512,
        8, 262144L, 32768L, 4096L, 0L, 262144L, 64L, 0L, 0, 1.0f);
    gemm_bf16<false><<<dim3(4, 4, 8), blk, 0, stream>>>(Tbuf, Wo2, nullptr, Mbuf,
        512, 512, 512, 512, 512, 512,
        1, 262144L, 0L, 262144L, 0L, 262144L, 0L, 0L, 0, 1.0f);
    bqS_kernel<<<dim3(64), dim3(64), 0, stream>>>(bq2, Sbuf, r2, 8, 64);
    rowmat_kernel<<<dim3(8, 2), blk, 0, stream>>>(r2, Wo2, bo2, c2,
        512, 512, 512L, 262144L, 512L);

    // ---- Fold final projection ----
    gemm_bf16<false><<<dim3(4, 4, 8), blk, 0, stream>>>(Mbuf, Wo, nullptr, M2p,
        512, 512, 512, 512, 512, 512,
        1, 262144L, 0L, 0L, 0L, 262144L, 0L, 0L, 0, 1.0f);
    rowmat_kernel<<<dim3(8, 2), blk, 0, stream>>>(c2, Wo, bo, c2p,
        512, 512, 512L, 0L, 0L);

    // out[g] = o1[g] @ M2p[g] + c2p[g]
    gemm_bf16<false><<<dim3(4, 16, 8), blk, 0, stream>>>(o1b, M2p, c2p, out,
        2048, 512, 512, 512, 512, 512,
        1, 1048576L, 0L, 262144L, 0L, 1048576L, 0L, 512L, 1, 1.0f);
}

// Round 3
// 852.187 us; speedup vs baseline: 2.8694x; 1.8181x over previous
//
#include <hip/hip_runtime.h>

// N=2048, D=512, A=64, NQ=8, G1=G2=8, A1=128.
// Algebra (no softmax): ctx = q @ (K^T V)/sqrt(a) => per-group fold:
//   S[g] = (xWk+bk)^T (xWv+bv)/sqrt(a);  M[g] = sum_q Wq[g,q] S[g] Wo_q[g,q]
//   o[g] = x M[g] + c[g];  tier2 same;  final @Wo folds into M2' = M2 Wo.
// ~34 GFLOP of GEMMs. bf16 MFMA GEMM (fp32 accum); latency-bound small ops
// (rowvec@mat, S split-K) parallelized with atomicAdd epilogues.

typedef __bf16 bf16x8 __attribute__((ext_vector_type(8)));
typedef __bf16 bf16x4 __attribute__((ext_vector_type(4)));
typedef float  f32x4  __attribute__((ext_vector_type(4)));

// ---------------- bf16 MFMA GEMM ----------------
// C = alpha * op(A) @ B (+ bias row). TA: A indexed as A[k,m] (lda = m-stride).
// blockIdx.z = b * ksplit + ks;  b: (go=b/divq, gi=b%divq); ptr += go*Out+gi*In.
// ksplit>1: each ks handles K/ksplit, atomicAdd into C (no bias; C pre-zeroed).
template<bool TA>
__global__ __launch_bounds__(256) void gemm_bf16(
    const float* __restrict__ A, const float* __restrict__ B,
    const float* __restrict__ bias, float* __restrict__ C,
    int M, int N, int K, int lda, int ldb, int ldc,
    int divq, int ksplit, long aOut, long aIn, long bOut, long bIn,
    long cOut, long cIn, long biasOut, int hasBias, float alpha)
{
    constexpr int BM = 128, BN = 128, BK = 32, LDP = BK + 8; // pad to 40
    __shared__ __bf16 As[BM][LDP];   // As[m][k]
    __shared__ __bf16 Bs[BN][LDP];   // Bs[n][k]

    int z  = blockIdx.z;
    int b  = z / ksplit, ks = z - b * ksplit;
    int go = b / divq, gi = b - go * divq;
    A += (long)go * aOut + (long)gi * aIn;
    B += (long)go * bOut + (long)gi * bIn;
    C += (long)go * cOut + (long)gi * cIn;
    if (hasBias) bias += (long)go * biasOut;

    int kChunk = K / ksplit;
    int kStart = ks * kChunk, kEnd = kStart + kChunk;

    int bm = blockIdx.y * BM, bn = blockIdx.x * BN;
    int tid  = threadIdx.x;
    int wave = tid >> 6, lane = tid & 63;
    int wm = (wave >> 1) * 64, wn = (wave & 1) * 64;
    int mrow = lane & 15, quad = lane >> 4;

    f32x4 acc[4][4];
    #pragma unroll
    for (int i = 0; i < 4; ++i)
        #pragma unroll
        for (int j = 0; j < 4; ++j)
            acc[i][j] = f32x4{0.f, 0.f, 0.f, 0.f};

    for (int k0 = kStart; k0 < kEnd; k0 += BK) {
        if (!TA) {
            #pragma unroll
            for (int t = 0; t < 4; ++t) {
                int idx = tid + t * 256;          // [0,1024)
                int row = idx >> 3, kq = idx & 7; // kq*4 in [0,32)
                bf16x4 v;
                if (bm + row < M) {
                    float4 f = *(const float4*)(A + (long)(bm + row) * lda + k0 + kq * 4);
                    v = bf16x4{(__bf16)f.x, (__bf16)f.y, (__bf16)f.z, (__bf16)f.w};
                } else {
                    v = bf16x4{(__bf16)0.f, (__bf16)0.f, (__bf16)0.f, (__bf16)0.f};
                }
                *(bf16x4*)&As[row][kq * 4] = v;
            }
        } else {
            #pragma unroll
            for (int t = 0; t < 4; ++t) {
                int idx = tid + t * 256;
                int kk = idx >> 5, mq = idx & 31;
                float4 f = {0.f, 0.f, 0.f, 0.f};
                if (bm + mq * 4 < M)
                    f = *(const float4*)(A + (long)(k0 + kk) * lda + bm + mq * 4);
                As[mq * 4 + 0][kk] = (__bf16)f.x;
                As[mq * 4 + 1][kk] = (__bf16)f.y;
                As[mq * 4 + 2][kk] = (__bf16)f.z;
                As[mq * 4 + 3][kk] = (__bf16)f.w;
            }
        }
        #pragma unroll
        for (int t = 0; t < 4; ++t) {
            int idx = tid + t * 256;
            int kk = idx >> 5, nq = idx & 31;
            float4 f = {0.f, 0.f, 0.f, 0.f};
            if (bn + nq * 4 < N)
                f = *(const float4*)(B + (long)(k0 + kk) * ldb + bn + nq * 4);
            Bs[nq * 4 + 0][kk] = (__bf16)f.x;
            Bs[nq * 4 + 1][kk] = (__bf16)f.y;
            Bs[nq * 4 + 2][kk] = (__bf16)f.z;
            Bs[nq * 4 + 3][kk] = (__bf16)f.w;
        }
        __syncthreads();

        bf16x8 af[4], bfv[4];
        #pragma unroll
        for (int mt = 0; mt < 4; ++mt)
            af[mt] = *(const bf16x8*)&As[wm + mt * 16 + mrow][quad * 8];
        #pragma unroll
        for (int nt = 0; nt < 4; ++nt)
            bfv[nt] = *(const bf16x8*)&Bs[wn + nt * 16 + mrow][quad * 8];
        #pragma unroll
        for (int mt = 0; mt < 4; ++mt)
            #pragma unroll
            for (int nt = 0; nt < 4; ++nt)
                acc[mt][nt] = __builtin_amdgcn_mfma_f32_16x16x32_bf16(
                    af[mt], bfv[nt], acc[mt][nt], 0, 0, 0);
        __syncthreads();
    }

    #pragma unroll
    for (int mt = 0; mt < 4; ++mt) {
        #pragma unroll
        for (int r = 0; r < 4; ++r) {
            int row = bm + wm + mt * 16 + quad * 4 + r;
            if (row >= M) continue;
            #pragma unroll
            for (int nt = 0; nt < 4; ++nt) {
                int col = bn + wn + nt * 16 + mrow;
                if (col >= N) continue;
                float v = acc[mt][nt][r] * alpha;
                if (ksplit == 1) {
                    if (hasBias) v += bias[col];
                    C[(long)row * ldc + col] = v;
                } else {
                    atomicAdd(&C[(long)row * ldc + col], v);
                }
            }
        }
    }
}

// out[b, d] += sum_f r[b,f] * W[(b/divq)*wOut + (b%divq)*wIn + f*Dd + d]
// grid: (batches, Dd/DL, fslices); 256 threads = DL d-lanes x (256/DL) f-subs.
// out must be pre-initialized (bias or zero).
__global__ __launch_bounds__(256) void rowvec_mat(
    const float* __restrict__ r, const float* __restrict__ W,
    float* __restrict__ out,
    int F, int Dd, int DL, int divq,
    long rStride, long wOut, long wIn, long outStride, int fslices)
{
    int b  = blockIdx.x;
    int go = b / divq, gi = b - go * divq;
    const float* rg = r + (long)b * rStride;
    const float* Wg = W + (long)go * wOut + (long)gi * wIn;
    int nsub = 256 / DL;
    int dl   = threadIdx.x % DL;
    int fsub = threadIdx.x / DL;
    int d = blockIdx.y * DL + dl;
    int fcount = F / (fslices * nsub);
    int f0 = blockIdx.z * (F / fslices) + fsub * fcount;
    float s = 0.f;
    for (int f = f0; f < f0 + fcount; ++f)
        s += rg[f] * Wg[(long)f * Dd + d];
    __shared__ float red[256];
    red[threadIdx.x] = s;
    __syncthreads();
    if (fsub == 0) {
        float t = s;
        for (int u = 1; u < nsub; ++u) t += red[u * DL + dl];
        atomicAdd(&out[(long)b * outStride + d], t);
    }
}

// out[b, d] = bias ? bias[(b)*bStride + d] : 0
__global__ void vec_init(float* __restrict__ out, const float* __restrict__ bias,
                         int Dd, long outStride, long bStride)
{
    int b = blockIdx.x;
    for (int d = threadIdx.x; d < Dd; d += blockDim.x)
        out[(long)b * outStride + d] = bias ? bias[(long)b * bStride + d] : 0.f;
}

extern "C" void kernel_launch(void* const* d_in, const int* in_sizes, int n_in,
                              void* d_out, int out_size, void* d_ws, size_t ws_size,
                              hipStream_t stream)
{
    const float* x   = (const float*)d_in[0];
    const float* Wq1 = (const float*)d_in[1];
    const float* bq1 = (const float*)d_in[2];
    const float* Wk1 = (const float*)d_in[3];
    const float* bk1 = (const float*)d_in[4];
    const float* Wv1 = (const float*)d_in[5];
    const float* bv1 = (const float*)d_in[6];
    const float* Wo1 = (const float*)d_in[7];
    const float* bo1 = (const float*)d_in[8];
    const float* Wq2 = (const float*)d_in[9];
    const float* bq2 = (const float*)d_in[10];
    const float* Wk2 = (const float*)d_in[11];
    const float* bk2 = (const float*)d_in[12];
    const float* Wv2 = (const float*)d_in[13];
    const float* bv2 = (const float*)d_in[14];
    const float* Wo2 = (const float*)d_in[15];
    const float* bo2 = (const float*)d_in[16];
    const float* Wo  = (const float*)d_in[17];
    const float* bo  = (const float*)d_in[18];
    float* out = (float*)d_out;
    float* ws  = (float*)d_ws;

    size_t off = 0;
    float* Kbuf = ws + off; off += 8L * 2048 * 128;
    float* Vbuf = ws + off; off += 8L * 2048 * 128;
    float* Sbuf = ws + off; off += 8L * 128 * 128;
    float* Tbuf = ws + off; off += 8L * 512 * 1024;
    float* Mbuf = ws + off; off += 8L * 512 * 512;
    float* o1b  = ws + off; off += 8L * 2048 * 512;
    float* M2p  = ws + off; off += 8L * 512 * 512;
    float* r1   = ws + off; off += 8L * 1024;
    float* c1   = ws + off; off += 8L * 512;
    float* r2   = ws + off; off += 8L * 512;
    float* c2   = ws + off; off += 8L * 512;
    float* c2p  = ws + off; off += 8L * 512;
    (void)ws_size; (void)n_in; (void)in_sizes; (void)out_size;

    dim3 blk(256);
    const float inv_sqrt_a1 = 0.08838834764831845f;  // 1/sqrt(128)
    const float inv_sqrt_a2 = 0.125f;                // 1/sqrt(64)

    // ---- Tier 1 ----
    gemm_bf16<false><<<dim3(1, 16, 8), blk, 0, stream>>>(x, Wk1, bk1, Kbuf,
        2048, 128, 512, 512, 128, 128,
        1, 1, 0L, 0L, 65536L, 0L, 262144L, 0L, 128L, 1, 1.0f);
    gemm_bf16<false><<<dim3(1, 16, 8), blk, 0, stream>>>(x, Wv1, bv1, Vbuf,
        2048, 128, 512, 512, 128, 128,
        1, 1, 0L, 0L, 65536L, 0L, 262144L, 0L, 128L, 1, 1.0f);
    // S1 = K1^T V1 / sqrt(128), split-K x16, atomic accumulate
    hipMemsetAsync(Sbuf, 0, 8L * 128 * 128 * sizeof(float), stream);
    gemm_bf16<true><<<dim3(1, 1, 128), blk, 0, stream>>>(Kbuf, Vbuf, nullptr, Sbuf,
        128, 128, 2048, 128, 128, 128,
        1, 16, 262144L, 0L, 262144L, 0L, 16384L, 0L, 0L, 0, inv_sqrt_a1);
    gemm_bf16<false><<<dim3(1, 4, 64), blk, 0, stream>>>(Wq1, Sbuf, nullptr, Tbuf,
        512, 128, 128, 128, 128, 1024,
        8, 1, 524288L, 65536L, 16384L, 0L, 524288L, 128L, 0L, 0, 1.0f);
    gemm_bf16<false><<<dim3(4, 4, 8), blk, 0, stream>>>(Tbuf, Wo1, nullptr, Mbuf,
        512, 512, 1024, 1024, 512, 512,
        1, 1, 524288L, 0L, 524288L, 0L, 262144L, 0L, 0L, 0, 1.0f);
    // r1[g,q*128+a] = bq1[g,q] @ S1[g];  c1[g] = r1[g] @ Wo1[g] + bo1[g]
    vec_init<<<dim3(64), blk, 0, stream>>>(r1, nullptr, 128, 128L, 0L);
    rowvec_mat<<<dim3(64, 1, 1), blk, 0, stream>>>(bq1, Sbuf, r1,
        128, 128, 128, 8, 128L, 16384L, 0L, 128L, 1);
    vec_init<<<dim3(8), blk, 0, stream>>>(c1, bo1, 512, 512L, 512L);
    rowvec_mat<<<dim3(8, 4, 8), blk, 0, stream>>>(r1, Wo1, c1,
        1024, 512, 128, 1, 1024L, 524288L, 0L, 512L, 8);
    gemm_bf16<false><<<dim3(4, 16, 8), blk, 0, stream>>>(x, Mbuf, c1, o1b,
        2048, 512, 512, 512, 512, 512,
        1, 1, 0L, 0L, 262144L, 0L, 1048576L, 0L, 512L, 1, 1.0f);

    // ---- Tier 2 ----
    gemm_bf16<false><<<dim3(1, 16, 8), blk, 0, stream>>>(o1b, Wk2, bk2, Kbuf,
        2048, 64, 512, 512, 64, 64,
        1, 1, 1048576L, 0L, 32768L, 0L, 131072L, 0L, 64L, 1, 1.0f);
    gemm_bf16<false><<<dim3(1, 16, 8), blk, 0, stream>>>(o1b, Wv2, bv2, Vbuf,
        2048, 64, 512, 512, 64, 64,
        1, 1, 1048576L, 0L, 32768L, 0L, 131072L, 0L, 64L, 1, 1.0f);
    hipMemsetAsync(Sbuf, 0, 8L * 64 * 64 * sizeof(float), stream);
    gemm_bf16<true><<<dim3(1, 1, 128), blk, 0, stream>>>(Kbuf, Vbuf, nullptr, Sbuf,
        64, 64, 2048, 64, 64, 64,
        1, 16, 131072L, 0L, 131072L, 0L, 4096L, 0L, 0L, 0, inv_sqrt_a2);
    gemm_bf16<false><<<dim3(1, 4, 64), blk, 0, stream>>>(Wq2, Sbuf, nullptr, Tbuf,
        512, 64, 64, 64, 64, 512,
        8, 1, 262144L, 32768L, 4096L, 0L, 262144L, 64L, 0L, 0, 1.0f);
    gemm_bf16<false><<<dim3(4, 4, 8), blk, 0, stream>>>(Tbuf, Wo2, nullptr, Mbuf,
        512, 512, 512, 512, 512, 512,
        1, 1, 262144L, 0L, 262144L, 0L, 262144L, 0L, 0L, 0, 1.0f);
    vec_init<<<dim3(64), blk, 0, stream>>>(r2, nullptr, 64, 64L, 0L);
    rowvec_mat<<<dim3(64, 1, 1), blk, 0, stream>>>(bq2, Sbuf, r2,
        64, 64, 64, 8, 64L, 4096L, 0L, 64L, 1);
    vec_init<<<dim3(8), blk, 0, stream>>>(c2, bo2, 512, 512L, 512L);
    rowvec_mat<<<dim3(8, 4, 4), blk, 0, stream>>>(r2, Wo2, c2,
        512, 512, 128, 1, 512L, 262144L, 0L, 512L, 4);

    // ---- Fold final projection ----
    gemm_bf16<false><<<dim3(4, 4, 8), blk, 0, stream>>>(Mbuf, Wo, nullptr, M2p,
        512, 512, 512, 512, 512, 512,
        1, 1, 262144L, 0L, 0L, 0L, 262144L, 0L, 0L, 0, 1.0f);
    vec_init<<<dim3(8), blk, 0, stream>>>(c2p, bo, 512, 512L, 0L);
    rowvec_mat<<<dim3(8, 4, 4), blk, 0, stream>>>(c2, Wo, c2p,
        512, 512, 128, 1, 512L, 0L, 0L, 512L, 4);

    // out[g] = o1[g] @ M2p[g] + c2p[g]
    gemm_bf16<false><<<dim3(4, 16, 8), blk, 0, stream>>>(o1b, M2p, c2p, out,
        2048, 512, 512, 512, 512, 512,
        1, 1, 1048576L, 0L, 262144L, 0L, 1048576L, 0L, 512L, 1, 1.0f);
}

// Round 5
// 390.276 us; speedup vs baseline: 6.2654x; 2.1835x over previous
//
#include <hip/hip_runtime.h>

// N=2048, D=512, A=64, NQ=8, G1=G2=8, A1=128.
// Algebra (no softmax): ctx = q (K^T V)/sqrt(a) => per-group fold:
//   S[g]=(xWk+bk)^T(xWv+bv)/sqrt(a); M[g]=sum_q Wq S Wo_q; o[g]=x M[g]+c[g];
//   tier2 same; final @Wo folds into M2p = M2 Wo.  ~34 GFLOP of GEMMs.
// All GEMMs consume bf16 k-major operands (C = A.B^T); a single prep pass
// converts/transposes weights; each GEMM's epilogue writes the layout its
// consumer needs (mode 2 = transposed bf16). No LDS transposes -> no bank
// conflicts. 64^2 tiles (>=256 blocks) for small GEMMs, 128^2 for the fat ones.
// R5 FIX: tier-2 K2^T/V2^T need [8][64][2048] = 1,048,576 elems EACH; R4
// allocated 524,288 -> buffer overflow clobbered STb2/T2b (absmax 5096).
// Now aliased into tier-1 Ktb (dead after S1 GEMM), which also trims total
// workspace to ~82.3 MB.

typedef __bf16 bf16x8 __attribute__((ext_vector_type(8)));
typedef float  f32x4  __attribute__((ext_vector_type(4)));

// ---------------- bf16 MFMA GEMM, C = alpha*(A.B^T) (+bias) ----------------
// A: bf16 [M][K] lda;  B: bf16 [N][K] ldb (k-major both).
// blockIdx.z = b*ksplit + ks; b -> (go=b/divq, gi=b%divq); ptr += go*Out+gi*In.
// mode: 0=f32 C[m][n], 1=bf16 C[m][n], 2=bf16 C[n][m] (ldc=M), 3=f32 atomicAdd.
// All dims assumed multiples of tile sizes (true for this problem).
template<int BM, int BN>
__global__ __launch_bounds__(256) void gemm(
    const __bf16* __restrict__ A, const __bf16* __restrict__ B,
    const float* __restrict__ bias, void* __restrict__ Cv,
    int K, int lda, int ldb, int ldc,
    int divq, int ksplit,
    long aOut, long aIn, long bOut, long bIn, long cOut, long cIn,
    long biasOut, long biasIn, int hasBias, int mode, float alpha)
{
    constexpr int MT = BM / 32, NT = BN / 32;
    __shared__ __bf16 As[BM][32];
    __shared__ __bf16 Bs[BN][32];

    int z  = blockIdx.z;
    int b  = z / ksplit, ks = z - b * ksplit;
    int go = b / divq,  gi = b - go * divq;
    A += go * aOut + gi * aIn;
    B += go * bOut + gi * bIn;
    long cBase = go * cOut + gi * cIn;
    if (hasBias) bias += go * biasOut + gi * biasIn;

    int kChunk = K / ksplit;
    int k0 = ks * kChunk, kEnd = k0 + kChunk;

    int bm = blockIdx.y * BM, bn = blockIdx.x * BN;
    int tid = threadIdx.x, wave = tid >> 6, lane = tid & 63;
    int wm = (wave >> 1) * (BM / 2), wn = (wave & 1) * (BN / 2);
    int mrow = lane & 15, quad = lane >> 4;

    f32x4 acc[MT][NT];
    #pragma unroll
    for (int i = 0; i < MT; ++i)
        #pragma unroll
        for (int j = 0; j < NT; ++j)
            acc[i][j] = f32x4{0.f, 0.f, 0.f, 0.f};

    for (; k0 < kEnd; k0 += 32) {
        __syncthreads();   // protect previous iter's frag reads
        #pragma unroll
        for (int t = 0; t < BM / 64; ++t) {
            int c = tid + t * 256;          // BM*4 chunks of 8 bf16
            int row = c >> 2, kq = c & 3;
            *(bf16x8*)&As[row][kq * 8] =
                *(const bf16x8*)(A + (long)(bm + row) * lda + k0 + kq * 8);
        }
        #pragma unroll
        for (int t = 0; t < BN / 64; ++t) {
            int c = tid + t * 256;
            int row = c >> 2, kq = c & 3;
            *(bf16x8*)&Bs[row][kq * 8] =
                *(const bf16x8*)(B + (long)(bn + row) * ldb + k0 + kq * 8);
        }
        __syncthreads();

        bf16x8 af[MT], bfv[NT];
        #pragma unroll
        for (int mt = 0; mt < MT; ++mt)
            af[mt] = *(const bf16x8*)&As[wm + mt * 16 + mrow][quad * 8];
        #pragma unroll
        for (int nt = 0; nt < NT; ++nt)
            bfv[nt] = *(const bf16x8*)&Bs[wn + nt * 16 + mrow][quad * 8];
        #pragma unroll
        for (int mt = 0; mt < MT; ++mt)
            #pragma unroll
            for (int nt = 0; nt < NT; ++nt)
                acc[mt][nt] = __builtin_amdgcn_mfma_f32_16x16x32_bf16(
                    af[mt], bfv[nt], acc[mt][nt], 0, 0, 0);
    }

    #pragma unroll
    for (int mt = 0; mt < MT; ++mt) {
        #pragma unroll
        for (int r = 0; r < 4; ++r) {
            int row = bm + wm + mt * 16 + quad * 4 + r;
            #pragma unroll
            for (int nt = 0; nt < NT; ++nt) {
                int col = bn + wn + nt * 16 + mrow;
                float v = acc[mt][nt][r] * alpha;
                if (hasBias) v += bias[col];
                if (mode == 0)
                    ((float*)Cv)[cBase + (long)row * ldc + col] = v;
                else if (mode == 1)
                    ((__bf16*)Cv)[cBase + (long)row * ldc + col] = (__bf16)v;
                else if (mode == 2)
                    ((__bf16*)Cv)[cBase + (long)col * ldc + row] = (__bf16)v;
                else
                    atomicAdd(&((float*)Cv)[cBase + (long)row * ldc + col], v);
            }
        }
    }
}

// ---------------- prep: one launch does all converts/transposes/inits ------
// mode 0: fp32 [Bc][R][C] -> bf16 [Bc][C][R] (transpose; R,C mult of 32)
// mode 1: fp32 -> bf16 flat (Bc*R*C, mult of 1024)
// mode 2: fp32 copy flat; mode 3: fp32 broadcast (src[idx%C]); mode 4: zero
struct PD { const float* s; void* d; int R, C, Bc, mode, blocks; };
struct PArgs { PD p[20]; int n; };

__global__ __launch_bounds__(256) void prep(PArgs a)
{
    __shared__ float tile[32][33];
    int bid = blockIdx.x;
    int i = 0;
    while (i < a.n && bid >= a.p[i].blocks) { bid -= a.p[i].blocks; ++i; }
    if (i >= a.n) return;
    PD d = a.p[i];
    int t = threadIdx.x;
    if (d.mode == 0) {
        int tC = d.C >> 5, tR = d.R >> 5;
        int batch = bid / (tC * tR), rem = bid - batch * (tC * tR);
        int tyo = rem / tC, txo = rem - tyo * tC;
        const float* src = d.s + (long)batch * d.R * d.C;
        __bf16* dst = (__bf16*)d.d + (long)batch * d.R * d.C;
        int tx = t & 31, ty = t >> 5;
        int r0 = tyo * 32, c0 = txo * 32;
        #pragma unroll
        for (int u = 0; u < 4; ++u)
            tile[ty + 8 * u][tx] = src[(long)(r0 + ty + 8 * u) * d.C + c0 + tx];
        __syncthreads();
        #pragma unroll
        for (int u = 0; u < 4; ++u)
            dst[(long)(c0 + ty + 8 * u) * d.R + r0 + tx] = (__bf16)tile[tx][ty + 8 * u];
    } else if (d.mode == 1) {
        long idx = ((long)bid * 256 + t) * 4;
        long total = (long)d.Bc * d.R * d.C;
        if (idx < total) {
            float4 f = *(const float4*)(d.s + idx);
            __bf16* o = (__bf16*)d.d + idx;
            o[0] = (__bf16)f.x; o[1] = (__bf16)f.y;
            o[2] = (__bf16)f.z; o[3] = (__bf16)f.w;
        }
    } else {
        long idx = (long)bid * 256 + t;
        long total = (long)d.Bc * d.R * d.C;
        if (idx < total) {
            float* o = (float*)d.d;
            if (d.mode == 2)      o[idx] = d.s[idx];
            else if (d.mode == 3) o[idx] = d.s[idx % d.C];
            else                  o[idx] = 0.f;
        }
    }
}

// out[b,d] += sum_f r[b,f] * W[go*wOut + gi*wIn + f*fStr + d*dStr]
__global__ __launch_bounds__(256) void rowvec_mat(
    const float* __restrict__ r, const float* __restrict__ W,
    float* __restrict__ out,
    int F, int Dd, int DL, int divq,
    long rStride, long wOut, long wIn, long fStr, long dStr,
    long outStride, int fslices)
{
    int b = blockIdx.x, go = b / divq, gi = b - go * divq;
    const float* rg = r + (long)b * rStride;
    const float* Wg = W + go * wOut + gi * wIn;
    int nsub = 256 / DL;
    int dl = threadIdx.x % DL, fsub = threadIdx.x / DL;
    int d = blockIdx.y * DL + dl;
    int fcount = F / (fslices * nsub);
    int f0 = blockIdx.z * (F / fslices) + fsub * fcount;
    float s = 0.f;
    for (int f = f0; f < f0 + fcount; ++f)
        s += rg[f] * Wg[f * fStr + (long)d * dStr];
    __shared__ float red[256];
    red[threadIdx.x] = s;
    __syncthreads();
    if (fsub == 0) {
        float tt = s;
        for (int u = 1; u < nsub; ++u) tt += red[u * DL + dl];
        atomicAdd(&out[(long)b * outStride + d], tt);
    }
}

__global__ void conv_f2b(const float* __restrict__ s, __bf16* __restrict__ d, long n)
{
    long i = ((long)blockIdx.x * 256 + threadIdx.x) * 4;
    if (i < n) {
        float4 f = *(const float4*)(s + i);
        d[i] = (__bf16)f.x; d[i + 1] = (__bf16)f.y;
        d[i + 2] = (__bf16)f.z; d[i + 3] = (__bf16)f.w;
    }
}

extern "C" void kernel_launch(void* const* d_in, const int* in_sizes, int n_in,
                              void* d_out, int out_size, void* d_ws, size_t ws_size,
                              hipStream_t stream)
{
    const float* x   = (const float*)d_in[0];
    const float* Wq1 = (const float*)d_in[1];
    const float* bq1 = (const float*)d_in[2];
    const float* Wk1 = (const float*)d_in[3];
    const float* bk1 = (const float*)d_in[4];
    const float* Wv1 = (const float*)d_in[5];
    const float* bv1 = (const float*)d_in[6];
    const float* Wo1 = (const float*)d_in[7];
    const float* bo1 = (const float*)d_in[8];
    const float* Wq2 = (const float*)d_in[9];
    const float* bq2 = (const float*)d_in[10];
    const float* Wk2 = (const float*)d_in[11];
    const float* bk2 = (const float*)d_in[12];
    const float* Wv2 = (const float*)d_in[13];
    const float* bv2 = (const float*)d_in[14];
    const float* Wo2 = (const float*)d_in[15];
    const float* bo2 = (const float*)d_in[16];
    const float* Wo  = (const float*)d_in[17];
    const float* bo  = (const float*)d_in[18];
    (void)in_sizes; (void)n_in; (void)out_size; (void)ws_size;

    // ---- workspace carve (bf16 first, then fp32) ----
    __bf16* wb = (__bf16*)d_ws;
    long o = 0;
    __bf16* xb    = wb + o; o += 1048576;            // x bf16 [2048][512]
    __bf16* Wk1t  = wb + o; o += 524288;             // [g][128][512]
    __bf16* Wv1t  = wb + o; o += 524288;             //   (contiguous after Wk1t)
    __bf16* Wq1b  = wb + o; o += 4194304;            // [g][q][512][128]
    __bf16* Wo1t  = wb + o; o += 4194304;            // [g][512][1024]
    __bf16* Wk2t  = wb + o; o += 262144;             // [g][64][512]
    __bf16* Wv2t  = wb + o; o += 262144;             //   (contiguous)
    __bf16* Wq2b  = wb + o; o += 2097152;            // [g][q][512][64]
    __bf16* Wo2t  = wb + o; o += 2097152;            // [g][512][512]
    __bf16* Wot   = wb + o; o += 262144;             // [512][512] (Wo^T)
    __bf16* Ktb   = wb + o; o += 2097152;            // K1^T [g][128][2048]
    __bf16* Vtb   = wb + o; o += 2097152;            //   (contiguous)
    __bf16* STb1  = wb + o; o += 131072;             // S1^T bf16 [g][128][128]
    __bf16* T1b   = wb + o; o += 4194304;            // [g][512][1024]
    __bf16* M1t   = wb + o; o += 2097152;            // M1^T [g][512][512]
    __bf16* o1b   = wb + o; o += 8388608;            // o1 bf16 [g][2048][512]
    // K2^T/V2^T: [g][64][2048] = 1,048,576 elems EACH (R4 under-allocated!).
    // Alias into Ktb/Vtb: K1^T/V1^T are dead after the S1 GEMM.
    __bf16* K2tb  = Ktb;                             // K2^T [g][64][2048]
    __bf16* V2tb  = Ktb + 1048576;                   // V2^T [g][64][2048]
    __bf16* STb2  = wb + o; o += 32768;              // S2^T bf16 [g][64][64]
    __bf16* T2b   = wb + o; o += 2097152;            // [g][512][512]
    __bf16* M2b   = wb + o; o += 2097152;            // M2 bf16 [g][512][512]
    __bf16* M2pt  = wb + o; o += 2097152;            // M2p^T [g][512][512]
    float* wf = (float*)(wb + o);
    long p = 0;
    float* STf1 = wf + p; p += 131072;               // S1^T fp32
    float* STf2 = wf + p; p += 32768;
    float* kvb1 = wf + p; p += 2048;                 // [bk1|bv1] 16x128
    float* kvb2 = wf + p; p += 1024;                 // [bk2|bv2] 16x64
    float* r1   = wf + p; p += 8192;                 // [64][128]
    float* c1   = wf + p; p += 4096;                 // [8][512]
    float* r2   = wf + p; p += 4096;                 // [64][64]
    float* c2   = wf + p; p += 4096;
    float* c2p  = wf + p; p += 4096;

    // ---- prep descriptors ----
    PArgs pa; int nd = 0; int totB = 0;
    auto add = [&](const float* s, void* d, int R, int C, int Bc, int mode) {
        int blocks;
        long total = (long)Bc * R * C;
        if (mode == 0) blocks = Bc * (R >> 5) * (C >> 5);
        else if (mode == 1) blocks = (int)(total / 1024);
        else blocks = (int)((total + 255) / 256);
        pa.p[nd] = PD{s, d, R, C, Bc, mode, blocks};
        ++nd; totB += blocks;
    };
    add(x,   xb,   2048, 512, 1, 1);     // convert x
    add(Wk1, Wk1t, 512, 128, 8, 0);      // transpose
    add(Wv1, Wv1t, 512, 128, 8, 0);
    add(Wq1, Wq1b, 512, 128, 64, 1);     // convert (flat over g,q)
    add(Wo1, Wo1t, 1024, 512, 8, 0);
    add(Wk2, Wk2t, 512, 64, 8, 0);
    add(Wv2, Wv2t, 512, 64, 8, 0);
    add(Wq2, Wq2b, 512, 64, 64, 1);
    add(Wo2, Wo2t, 512, 512, 8, 0);
    add(Wo,  Wot,  512, 512, 1, 0);
    add(bk1, kvb1,        1, 1024, 1, 2);
    add(bv1, kvb1 + 1024, 1, 1024, 1, 2);
    add(bk2, kvb2,        1, 512, 1, 2);
    add(bv2, kvb2 + 512,  1, 512, 1, 2);
    add(bo1, c1, 1, 4096, 1, 2);         // c1 = bo1 (rowvec adds on top)
    add(bo2, c2, 1, 4096, 1, 2);
    add(bo,  c2p, 8, 512, 1, 3);         // broadcast bo across 8 groups
    add(nullptr, r1, 1, 8192, 1, 4);     // zero
    add(nullptr, r2, 1, 4096, 1, 4);
    pa.n = nd;
    prep<<<dim3(totB), dim3(256), 0, stream>>>(pa);

    const float isa1 = 0.08838834764831845f;  // 1/sqrt(128)
    dim3 blk(256);

    // ---- Tier 1 ----
    // K1^T,V1^T = (x @ Wk/Wv + b)^T : fused, b=0..15 -> Kt|Vt
    gemm<64,64><<<dim3(2, 32, 16), blk, 0, stream>>>(xb, Wk1t, kvb1, Ktb,
        512, 512, 512, 2048, 1, 1,
        0L, 0L, 65536L, 0L, 262144L, 0L, 128L, 0L, 1, 2, 1.0f);
    // S1^T = V1^T . K1 (split-K x8, atomic)
    hipMemsetAsync(STf1, 0, 131072 * sizeof(float), stream);
    gemm<64,64><<<dim3(2, 2, 64), blk, 0, stream>>>(Vtb, Ktb, nullptr, STf1,
        2048, 2048, 2048, 128, 1, 8,
        262144L, 0L, 262144L, 0L, 16384L, 0L, 0L, 0L, 0, 3, isa1);
    conv_f2b<<<dim3(128), blk, 0, stream>>>(STf1, STb1, 131072);
    // r1[gq] = bq1 @ S1 ; c1[g] = r1 @ Wo1 + bo1
    rowvec_mat<<<dim3(64, 1, 1), blk, 0, stream>>>(bq1, STf1, r1,
        128, 128, 128, 8, 128L, 16384L, 0L, 1L, 128L, 128L, 1);
    rowvec_mat<<<dim3(8, 4, 8), blk, 0, stream>>>(r1, Wo1, c1,
        1024, 512, 128, 1, 1024L, 524288L, 0L, 512L, 1L, 512L, 8);
    // T1[g][:,q*128:] = Wq1[g,q] . S1  (B = S1^T k-major)
    gemm<64,64><<<dim3(2, 8, 64), blk, 0, stream>>>(Wq1b, STb1, nullptr, T1b,
        128, 128, 128, 1024, 8, 1,
        524288L, 65536L, 16384L, 0L, 524288L, 128L, 0L, 0L, 0, 1, 1.0f);
    // M1^T = (T1 . Wo1)^T
    gemm<64,64><<<dim3(8, 8, 8), blk, 0, stream>>>(T1b, Wo1t, nullptr, M1t,
        1024, 1024, 1024, 512, 1, 1,
        524288L, 0L, 524288L, 0L, 262144L, 0L, 0L, 0L, 0, 2, 1.0f);
    // o1 = x . M1 + c1  (bf16 out)
    gemm<128,128><<<dim3(4, 16, 8), blk, 0, stream>>>(xb, M1t, c1, o1b,
        512, 512, 512, 512, 1, 1,
        0L, 0L, 262144L, 0L, 1048576L, 0L, 512L, 0L, 1, 1, 1.0f);

    // ---- Tier 2 ----
    // K2^T,V2^T fused: b=0..15, go=b/8 selects Wk2t|Wv2t (and K2tb|V2tb
    // halves via cOut=1048576), gi=b%8 = group
    gemm<64,64><<<dim3(1, 32, 16), blk, 0, stream>>>(o1b, Wk2t, kvb2, K2tb,
        512, 512, 512, 2048, 8, 1,
        0L, 1048576L, 262144L, 32768L, 1048576L, 131072L, 512L, 64L, 1, 2, 1.0f);
    hipMemsetAsync(STf2, 0, 32768 * sizeof(float), stream);
    gemm<64,64><<<dim3(1, 1, 128), blk, 0, stream>>>(V2tb, K2tb, nullptr, STf2,
        2048, 2048, 2048, 64, 1, 16,
        131072L, 0L, 131072L, 0L, 4096L, 0L, 0L, 0L, 0, 3, 0.125f);
    conv_f2b<<<dim3(32), blk, 0, stream>>>(STf2, STb2, 32768);
    rowvec_mat<<<dim3(64, 1, 1), blk, 0, stream>>>(bq2, STf2, r2,
        64, 64, 64, 8, 64L, 4096L, 0L, 1L, 64L, 64L, 1);
    rowvec_mat<<<dim3(8, 4, 4), blk, 0, stream>>>(r2, Wo2, c2,
        512, 512, 128, 1, 512L, 262144L, 0L, 512L, 1L, 512L, 4);
    gemm<64,64><<<dim3(1, 8, 64), blk, 0, stream>>>(Wq2b, STb2, nullptr, T2b,
        64, 64, 64, 512, 8, 1,
        262144L, 32768L, 4096L, 0L, 262144L, 64L, 0L, 0L, 0, 1, 1.0f);
    gemm<64,64><<<dim3(8, 8, 8), blk, 0, stream>>>(T2b, Wo2t, nullptr, M2b,
        512, 512, 512, 512, 1, 1,
        262144L, 0L, 262144L, 0L, 262144L, 0L, 0L, 0L, 0, 1, 1.0f);
    // M2p^T = (M2 . Wo)^T
    gemm<64,64><<<dim3(8, 8, 8), blk, 0, stream>>>(M2b, Wot, nullptr, M2pt,
        512, 512, 512, 512, 1, 1,
        262144L, 0L, 0L, 0L, 262144L, 0L, 0L, 0L, 0, 2, 1.0f);
    rowvec_mat<<<dim3(8, 4, 4), blk, 0, stream>>>(c2, Wo, c2p,
        512, 512, 128, 1, 512L, 0L, 0L, 512L, 1L, 512L, 4);

    // out = o1 . M2p + c2p  (fp32 -> d_out)
    gemm<128,128><<<dim3(4, 16, 8), blk, 0, stream>>>(o1b, M2pt, c2p, (float*)d_out,
        512, 512, 512, 512, 1, 1,
        1048576L, 0L, 262144L, 0L, 1048576L, 0L, 512L, 0L, 1, 0, 1.0f);
}

// Round 6
// 343.897 us; speedup vs baseline: 7.1103x; 1.1349x over previous
//
#include <hip/hip_runtime.h>

// N=2048, D=512, A=64, NQ=8, G1=G2=8, A1=128.
// Algebra (no softmax): ctx = q (K^T V)/sqrt(a) => per-group fold:
//   S[g]=(xWk+bk)^T(xWv+bv)/sqrt(a); M[g]=sum_q Wq S Wo_q; o[g]=x M[g]+c[g];
//   tier2 same; final @Wo folds into M2p = M2 Wo.  ~34 GFLOP of GEMMs.
// R6: (a) global_load_lds 16B async staging in the GEMM (LDS layout is
// tid*16B contiguous -> satisfies wave-uniform-base+lane*16 rule);
// (b) conv+r+c fused into one small_ops kernel per tier (r recomputed per
// block -> no cross-block dep, no atomics, no zero-init); (c) memsets gone
// (prep zeroes STf). 21 -> 15 dispatches.

typedef __bf16 bf16x8 __attribute__((ext_vector_type(8)));
typedef float  f32x4  __attribute__((ext_vector_type(4)));

// ---------------- bf16 MFMA GEMM, C = alpha*(A.B^T) (+bias) ----------------
// A: bf16 [M][K] lda;  B: bf16 [N][K] ldb (k-major both).
// blockIdx.z = b*ksplit + ks; b -> (go=b/divq, gi=b%divq); ptr += go*Out+gi*In.
// mode: 0=f32 C[m][n], 1=bf16 C[m][n], 2=bf16 C[n][m] (ldc=M), 3=f32 atomicAdd.
// All dims are exact tile multiples (no bounds checks).
template<int BM, int BN>
__global__ __launch_bounds__(256) void gemm(
    const __bf16* __restrict__ A, const __bf16* __restrict__ B,
    const float* __restrict__ bias, void* __restrict__ Cv,
    int K, int lda, int ldb, int ldc,
    int divq, int ksplit,
    long aOut, long aIn, long bOut, long bIn, long cOut, long cIn,
    long biasOut, long biasIn, int hasBias, int mode, float alpha)
{
    constexpr int MT = BM / 32, NT = BN / 32;
    __shared__ __bf16 As[BM][32];
    __shared__ __bf16 Bs[BN][32];

    int z  = blockIdx.z;
    int b  = z / ksplit, ks = z - b * ksplit;
    int go = b / divq,  gi = b - go * divq;
    A += go * aOut + gi * aIn;
    B += go * bOut + gi * bIn;
    long cBase = go * cOut + gi * cIn;
    if (hasBias) bias += go * biasOut + gi * biasIn;

    int kChunk = K / ksplit;
    int k0 = ks * kChunk, kEnd = k0 + kChunk;

    int bm = blockIdx.y * BM, bn = blockIdx.x * BN;
    int tid = threadIdx.x, wave = tid >> 6, lane = tid & 63;
    int wm = (wave >> 1) * (BM / 2), wn = (wave & 1) * (BN / 2);
    int mrow = lane & 15, quad = lane >> 4;

    f32x4 acc[MT][NT];
    #pragma unroll
    for (int i = 0; i < MT; ++i)
        #pragma unroll
        for (int j = 0; j < NT; ++j)
            acc[i][j] = f32x4{0.f, 0.f, 0.f, 0.f};

    for (; k0 < kEnd; k0 += 32) {
        __syncthreads();   // prev iter frag reads done before LDS overwrite
        // async global->LDS, 16B/lane; LDS byte offset == c*16 (contiguous)
        #pragma unroll
        for (int t = 0; t < BM / 64; ++t) {
            int c = tid + t * 256;
            int row = c >> 2, kq = c & 3;
            __builtin_amdgcn_global_load_lds(
                (const __attribute__((address_space(1))) void*)
                    (A + (long)(bm + row) * lda + k0 + kq * 8),
                (__attribute__((address_space(3))) void*)&As[row][kq * 8],
                16, 0, 0);
        }
        #pragma unroll
        for (int t = 0; t < BN / 64; ++t) {
            int c = tid + t * 256;
            int row = c >> 2, kq = c & 3;
            __builtin_amdgcn_global_load_lds(
                (const __attribute__((address_space(1))) void*)
                    (B + (long)(bn + row) * ldb + k0 + kq * 8),
                (__attribute__((address_space(3))) void*)&Bs[row][kq * 8],
                16, 0, 0);
        }
        __syncthreads();   // drains vmcnt for the lds-loads

        bf16x8 af[MT], bfv[NT];
        #pragma unroll
        for (int mt = 0; mt < MT; ++mt)
            af[mt] = *(const bf16x8*)&As[wm + mt * 16 + mrow][quad * 8];
        #pragma unroll
        for (int nt = 0; nt < NT; ++nt)
            bfv[nt] = *(const bf16x8*)&Bs[wn + nt * 16 + mrow][quad * 8];
        #pragma unroll
        for (int mt = 0; mt < MT; ++mt)
            #pragma unroll
            for (int nt = 0; nt < NT; ++nt)
                acc[mt][nt] = __builtin_amdgcn_mfma_f32_16x16x32_bf16(
                    af[mt], bfv[nt], acc[mt][nt], 0, 0, 0);
    }

    #pragma unroll
    for (int mt = 0; mt < MT; ++mt) {
        #pragma unroll
        for (int r = 0; r < 4; ++r) {
            int row = bm + wm + mt * 16 + quad * 4 + r;
            #pragma unroll
            for (int nt = 0; nt < NT; ++nt) {
                int col = bn + wn + nt * 16 + mrow;
                float v = acc[mt][nt][r] * alpha;
                if (hasBias) v += bias[col];
                if (mode == 0)
                    ((float*)Cv)[cBase + (long)row * ldc + col] = v;
                else if (mode == 1)
                    ((__bf16*)Cv)[cBase + (long)row * ldc + col] = (__bf16)v;
                else if (mode == 2)
                    ((__bf16*)Cv)[cBase + (long)col * ldc + row] = (__bf16)v;
                else
                    atomicAdd(&((float*)Cv)[cBase + (long)row * ldc + col], v);
            }
        }
    }
}

// ---------------- prep: converts/transposes/zeros, one launch ----------------
// mode 0: fp32 [Bc][R][C] -> bf16 [Bc][C][R] transpose (R,C mult of 32)
// mode 1: fp32 -> bf16 flat; mode 2: fp32 copy; mode 4: zero fp32
struct PD { const float* s; void* d; int R, C, Bc, mode, blocks; };
struct PArgs { PD p[20]; int n; };

__global__ __launch_bounds__(256) void prep(PArgs a)
{
    __shared__ float tile[32][33];
    int bid = blockIdx.x;
    int i = 0;
    while (i < a.n && bid >= a.p[i].blocks) { bid -= a.p[i].blocks; ++i; }
    if (i >= a.n) return;
    PD d = a.p[i];
    int t = threadIdx.x;
    if (d.mode == 0) {
        int tC = d.C >> 5, tR = d.R >> 5;
        int batch = bid / (tC * tR), rem = bid - batch * (tC * tR);
        int tyo = rem / tC, txo = rem - tyo * tC;
        const float* src = d.s + (long)batch * d.R * d.C;
        __bf16* dst = (__bf16*)d.d + (long)batch * d.R * d.C;
        int tx = t & 31, ty = t >> 5;
        int r0 = tyo * 32, c0 = txo * 32;
        #pragma unroll
        for (int u = 0; u < 4; ++u)
            tile[ty + 8 * u][tx] = src[(long)(r0 + ty + 8 * u) * d.C + c0 + tx];
        __syncthreads();
        #pragma unroll
        for (int u = 0; u < 4; ++u)
            dst[(long)(c0 + ty + 8 * u) * d.R + r0 + tx] = (__bf16)tile[tx][ty + 8 * u];
    } else if (d.mode == 1) {
        long idx = ((long)bid * 256 + t) * 4;
        long total = (long)d.Bc * d.R * d.C;
        if (idx < total) {
            float4 f = *(const float4*)(d.s + idx);
            __bf16* o = (__bf16*)d.d + idx;
            o[0] = (__bf16)f.x; o[1] = (__bf16)f.y;
            o[2] = (__bf16)f.z; o[3] = (__bf16)f.w;
        }
    } else {
        long idx = (long)bid * 256 + t;
        long total = (long)d.Bc * d.R * d.C;
        if (idx < total) {
            float* o = (float*)d.d;
            if (d.mode == 2) o[idx] = d.s[idx];
            else             o[idx] = 0.f;
        }
    }
}

// ---------------- small_ops: conv(STf->STb) + fused r,c per tier -----------
// blocks [0,nConv): bf16 convert of STf (4 floats/thread).
// blocks [nConv, nConv+256): 8 groups x 32 d-slices of 16.
//   r[f]=sum_c bq[g,q,c]*STf[g][a][c] recomputed per block (cheap);
//   c[g][d] = boA[g][d] + sum_f r[f]*WoT[g][d][f]   (WoT bf16, k-contiguous)
__global__ __launch_bounds__(256) void small_ops(
    const float* __restrict__ STf, __bf16* __restrict__ STb,
    const float* __restrict__ bq, const __bf16* __restrict__ WoT,
    const float* __restrict__ boA, float* __restrict__ cOut,
    int ad, int F, int nConv, long nS, long wG)
{
    int tid = threadIdx.x;
    if ((int)blockIdx.x < nConv) {
        long idx = ((long)blockIdx.x * 256 + tid) * 4;
        if (idx < nS) {
            float4 f = *(const float4*)(STf + idx);
            __bf16* o = STb + idx;
            o[0] = (__bf16)f.x; o[1] = (__bf16)f.y;
            o[2] = (__bf16)f.z; o[3] = (__bf16)f.w;
        }
        return;
    }
    int bid = blockIdx.x - nConv;
    int g = bid >> 5, slice = bid & 31;
    __shared__ float rL[1024];
    __shared__ float red[256];
    int nq = F / ad;
    const float* Sg = STf + (long)g * ad * ad;
    for (int f = tid; f < F; f += 256) {
        int q = f / ad, a = f - q * ad;
        const float* bv = bq + (long)(g * nq + q) * ad;
        const float* Sa = Sg + (long)a * ad;
        float s = 0.f;
        for (int c = 0; c < ad; c += 4) {
            float4 b4 = *(const float4*)(bv + c);
            float4 s4 = *(const float4*)(Sa + c);
            s += b4.x * s4.x + b4.y * s4.y + b4.z * s4.z + b4.w * s4.w;
        }
        rL[f] = s;
    }
    __syncthreads();
    int dl = tid & 15, fs = tid >> 4;
    int d = slice * 16 + dl;
    int fchunk = F >> 4;
    const __bf16* wrow = WoT + (long)g * wG + (long)d * F;
    float s = 0.f;
    for (int f0 = fs * fchunk; f0 < (fs + 1) * fchunk; f0 += 8) {
        bf16x8 w = *(const bf16x8*)(wrow + f0);
        s += rL[f0]     * (float)w[0] + rL[f0 + 1] * (float)w[1]
           + rL[f0 + 2] * (float)w[2] + rL[f0 + 3] * (float)w[3]
           + rL[f0 + 4] * (float)w[4] + rL[f0 + 5] * (float)w[5]
           + rL[f0 + 6] * (float)w[6] + rL[f0 + 7] * (float)w[7];
    }
    red[tid] = s;
    __syncthreads();
    if (fs == 0) {
        float t = s;
        #pragma unroll
        for (int u = 1; u < 16; ++u) t += red[u * 16 + dl];
        cOut[(long)g * 512 + d] = boA[(long)g * 512 + d] + t;
    }
}

// c2p[g][d] = bias[d] + sum_f v[g][f] * WT[d][f]   (grid: 8 x 32, F=512)
__global__ __launch_bounds__(256) void vecmat(
    const float* __restrict__ v, const __bf16* __restrict__ WT,
    const float* __restrict__ bias, float* __restrict__ outp)
{
    int g = blockIdx.x, slice = blockIdx.y;
    int tid = threadIdx.x;
    int dl = tid & 15, fs = tid >> 4;
    int d = slice * 16 + dl;
    const float* vg = v + (long)g * 512;
    const __bf16* wrow = WT + (long)d * 512;
    float s = 0.f;
    for (int f0 = fs * 32; f0 < (fs + 1) * 32; f0 += 8) {
        bf16x8 w = *(const bf16x8*)(wrow + f0);
        s += vg[f0]     * (float)w[0] + vg[f0 + 1] * (float)w[1]
           + vg[f0 + 2] * (float)w[2] + vg[f0 + 3] * (float)w[3]
           + vg[f0 + 4] * (float)w[4] + vg[f0 + 5] * (float)w[5]
           + vg[f0 + 6] * (float)w[6] + vg[f0 + 7] * (float)w[7];
    }
    __shared__ float red[256];
    red[tid] = s;
    __syncthreads();
    if (fs == 0) {
        float t = s;
        #pragma unroll
        for (int u = 1; u < 16; ++u) t += red[u * 16 + dl];
        outp[(long)g * 512 + d] = bias[d] + t;
    }
}

extern "C" void kernel_launch(void* const* d_in, const int* in_sizes, int n_in,
                              void* d_out, int out_size, void* d_ws, size_t ws_size,
                              hipStream_t stream)
{
    const float* x   = (const float*)d_in[0];
    const float* Wq1 = (const float*)d_in[1];
    const float* bq1 = (const float*)d_in[2];
    const float* Wk1 = (const float*)d_in[3];
    const float* bk1 = (const float*)d_in[4];
    const float* Wv1 = (const float*)d_in[5];
    const float* bv1 = (const float*)d_in[6];
    const float* Wo1 = (const float*)d_in[7];
    const float* bo1 = (const float*)d_in[8];
    const float* Wq2 = (const float*)d_in[9];
    const float* bq2 = (const float*)d_in[10];
    const float* Wk2 = (const float*)d_in[11];
    const float* bk2 = (const float*)d_in[12];
    const float* Wv2 = (const float*)d_in[13];
    const float* bv2 = (const float*)d_in[14];
    const float* Wo2 = (const float*)d_in[15];
    const float* bo2 = (const float*)d_in[16];
    const float* Wo  = (const float*)d_in[17];
    const float* bo  = (const float*)d_in[18];
    (void)in_sizes; (void)n_in; (void)out_size; (void)ws_size;

    // ---- workspace carve (bf16 first, then fp32) ----
    __bf16* wb = (__bf16*)d_ws;
    long o = 0;
    __bf16* xb    = wb + o; o += 1048576;            // x bf16 [2048][512]
    __bf16* Wk1t  = wb + o; o += 524288;             // [g][128][512]
    __bf16* Wv1t  = wb + o; o += 524288;             //   (contiguous)
    __bf16* Wq1b  = wb + o; o += 4194304;            // [g][q][512][128]
    __bf16* Wo1t  = wb + o; o += 4194304;            // [g][512][1024]
    __bf16* Wk2t  = wb + o; o += 262144;             // [g][64][512]
    __bf16* Wv2t  = wb + o; o += 262144;             //   (contiguous)
    __bf16* Wq2b  = wb + o; o += 2097152;            // [g][q][512][64]
    __bf16* Wo2t  = wb + o; o += 2097152;            // [g][512][512]
    __bf16* Wot   = wb + o; o += 262144;             // [512][512] (Wo^T)
    __bf16* Ktb   = wb + o; o += 2097152;            // K1^T [g][128][2048]
    __bf16* Vtb   = wb + o; o += 2097152;            //   (contiguous)
    __bf16* STb1  = wb + o; o += 131072;             // S1^T bf16
    __bf16* T1b   = wb + o; o += 4194304;            // [g][512][1024]
    __bf16* M1t   = wb + o; o += 2097152;            // M1^T
    __bf16* o1b   = wb + o; o += 8388608;            // o1 bf16 [g][2048][512]
    __bf16* K2tb  = Ktb;                             // alias: K2^T [g][64][2048]
    __bf16* V2tb  = Ktb + 1048576;                   // alias: V2^T
    __bf16* STb2  = wb + o; o += 32768;              // S2^T bf16
    __bf16* T2b   = wb + o; o += 2097152;            // [g][512][512]
    __bf16* M2b   = wb + o; o += 2097152;            // M2 bf16
    __bf16* M2pt  = wb + o; o += 2097152;            // M2p^T
    float* wf = (float*)(wb + o);
    long p = 0;
    float* STf1 = wf + p; p += 131072;               // S1^T fp32
    float* STf2 = wf + p; p += 32768;
    float* kvb1 = wf + p; p += 2048;                 // [bk1|bv1] 16x128
    float* kvb2 = wf + p; p += 1024;                 // [bk2|bv2] 16x64
    float* c1   = wf + p; p += 4096;                 // [8][512]
    float* c2   = wf + p; p += 4096;
    float* c2p  = wf + p; p += 4096;

    // ---- prep descriptors ----
    PArgs pa; int nd = 0; int totB = 0;
    auto add = [&](const float* s, void* d, int R, int C, int Bc, int mode) {
        int blocks;
        long total = (long)Bc * R * C;
        if (mode == 0) blocks = Bc * (R >> 5) * (C >> 5);
        else if (mode == 1) blocks = (int)(total / 1024);
        else blocks = (int)((total + 255) / 256);
        pa.p[nd] = PD{s, d, R, C, Bc, mode, blocks};
        ++nd; totB += blocks;
    };
    add(x,   xb,   2048, 512, 1, 1);
    add(Wq1, Wq1b, 512, 128, 64, 1);
    add(Wq2, Wq2b, 512, 64, 64, 1);
    add(Wk1, Wk1t, 512, 128, 8, 0);
    add(Wv1, Wv1t, 512, 128, 8, 0);
    add(Wo1, Wo1t, 1024, 512, 8, 0);
    add(Wk2, Wk2t, 512, 64, 8, 0);
    add(Wv2, Wv2t, 512, 64, 8, 0);
    add(Wo2, Wo2t, 512, 512, 8, 0);
    add(Wo,  Wot,  512, 512, 1, 0);
    add(bk1, kvb1,        1, 1024, 1, 2);
    add(bv1, kvb1 + 1024, 1, 1024, 1, 2);
    add(bk2, kvb2,        1, 512, 1, 2);
    add(bv2, kvb2 + 512,  1, 512, 1, 2);
    add(nullptr, STf1, 1, 131072, 1, 4);   // zero for atomic split-K
    add(nullptr, STf2, 1, 32768, 1, 4);
    pa.n = nd;
    prep<<<dim3(totB), dim3(256), 0, stream>>>(pa);

    const float isa1 = 0.08838834764831845f;  // 1/sqrt(128)
    dim3 blk(256);

    // ---- Tier 1 ----
    gemm<64,64><<<dim3(2, 32, 16), blk, 0, stream>>>(xb, Wk1t, kvb1, Ktb,
        512, 512, 512, 2048, 1, 1,
        0L, 0L, 65536L, 0L, 262144L, 0L, 128L, 0L, 1, 2, 1.0f);
    gemm<64,64><<<dim3(2, 2, 64), blk, 0, stream>>>(Vtb, Ktb, nullptr, STf1,
        2048, 2048, 2048, 128, 1, 8,
        262144L, 0L, 262144L, 0L, 16384L, 0L, 0L, 0L, 0, 3, isa1);
    small_ops<<<dim3(384), blk, 0, stream>>>(STf1, STb1, bq1, Wo1t, bo1, c1,
        128, 1024, 128, 131072L, 524288L);
    gemm<64,64><<<dim3(2, 8, 64), blk, 0, stream>>>(Wq1b, STb1, nullptr, T1b,
        128, 128, 128, 1024, 8, 1,
        524288L, 65536L, 16384L, 0L, 524288L, 128L, 0L, 0L, 0, 1, 1.0f);
    gemm<64,64><<<dim3(8, 8, 8), blk, 0, stream>>>(T1b, Wo1t, nullptr, M1t,
        1024, 1024, 1024, 512, 1, 1,
        524288L, 0L, 524288L, 0L, 262144L, 0L, 0L, 0L, 0, 2, 1.0f);
    gemm<128,128><<<dim3(4, 16, 8), blk, 0, stream>>>(xb, M1t, c1, o1b,
        512, 512, 512, 512, 1, 1,
        0L, 0L, 262144L, 0L, 1048576L, 0L, 512L, 0L, 1, 1, 1.0f);

    // ---- Tier 2 ----
    gemm<64,64><<<dim3(1, 32, 16), blk, 0, stream>>>(o1b, Wk2t, kvb2, K2tb,
        512, 512, 512, 2048, 8, 1,
        0L, 1048576L, 262144L, 32768L, 1048576L, 131072L, 512L, 64L, 1, 2, 1.0f);
    gemm<64,64><<<dim3(1, 1, 128), blk, 0, stream>>>(V2tb, K2tb, nullptr, STf2,
        2048, 2048, 2048, 64, 1, 16,
        131072L, 0L, 131072L, 0L, 4096L, 0L, 0L, 0L, 0, 3, 0.125f);
    small_ops<<<dim3(288), blk, 0, stream>>>(STf2, STb2, bq2, Wo2t, bo2, c2,
        64, 512, 32, 32768L, 262144L);
    vecmat<<<dim3(8, 32), blk, 0, stream>>>(c2, Wot, bo, c2p);
    gemm<64,64><<<dim3(1, 8, 64), blk, 0, stream>>>(Wq2b, STb2, nullptr, T2b,
        64, 64, 64, 512, 8, 1,
        262144L, 32768L, 4096L, 0L, 262144L, 64L, 0L, 0L, 0, 1, 1.0f);
    gemm<64,64><<<dim3(8, 8, 8), blk, 0, stream>>>(T2b, Wo2t, nullptr, M2b,
        512, 512, 512, 512, 1, 1,
        262144L, 0L, 262144L, 0L, 262144L, 0L, 0L, 0L, 0, 1, 1.0f);
    gemm<64,64><<<dim3(8, 8, 8), blk, 0, stream>>>(M2b, Wot, nullptr, M2pt,
        512, 512, 512, 512, 1, 1,
        262144L, 0L, 0L, 0L, 262144L, 0L, 0L, 0L, 0, 2, 1.0f);

    // out = o1 . M2p + c2p  (fp32 -> d_out)
    gemm<128,128><<<dim3(4, 16, 8), blk, 0, stream>>>(o1b, M2pt, c2p, (float*)d_out,
        512, 512, 512, 512, 1, 1,
        1048576L, 0L, 262144L, 0L, 1048576L, 0L, 512L, 0L, 1, 0, 1.0f);
}